// Round 9
// baseline (207.568 us; speedup 1.0000x reference)
//
#include <hip/hip_runtime.h>
#include <hip/hip_fp16.h>

// SSIM loss v8: both separable conv passes as banded MFMA GEMMs (f16 in,
// fp32 accum). Horizontal: H[48x64] = X[48x80] * WH[80x64] (band weights
// built per-lane). Vertical: OUT[32x64] = WV[32x48] * H[48x64]. H lives
// transposed in LDS (per-wave columns only -> NO inter-wave barrier).
// Frag maps (m89/m91-verified): A row=l&15; B col=l&15; C col=l&15,
// row=(l>>4)*4+reg. k-layout uncertainty cancels (same indexing on A & B).
// Inputs: img1, img2 float32 [16,3,512,512]. Output: scalar float32.

#define IMG     512
#define NPLANES 48
#define NPIX    (48*512*512)
#define RS      56            // ht row capacity (f16); 112 B, 16B-aligned

typedef _Float16 f16x8 __attribute__((ext_vector_type(8)));
typedef _Float16 f16x4 __attribute__((ext_vector_type(4)));
typedef float    f32x4 __attribute__((ext_vector_type(4)));

// Normalized 11-tap Gaussian (sigma=1.5).
constexpr float GW[11] = {
    0.00102837f, 0.00759877f, 0.03600077f, 0.10936070f, 0.21300553f,
    0.26601174f,
    0.21300553f, 0.10936070f, 0.03600077f, 0.00759877f, 0.00102837f
};

__device__ __forceinline__ _Float16 wl(const _Float16* wtab, int idx) {
    unsigned u = (unsigned)idx;
    return wtab[u > 10u ? 11u : u];     // slot 11 holds 0
}

__device__ __forceinline__ void loadrow8(const float* __restrict__ row,
                                         int colbase, bool rowok, float* b) {
    const bool fast = rowok && (colbase >= 0) && (colbase <= IMG - 8);
    if (fast) {
        float4 lo = *reinterpret_cast<const float4*>(row + colbase);
        float4 hi = *reinterpret_cast<const float4*>(row + colbase + 4);
        b[0]=lo.x; b[1]=lo.y; b[2]=lo.z; b[3]=lo.w;
        b[4]=hi.x; b[5]=hi.y; b[6]=hi.z; b[7]=hi.w;
    } else {
#pragma unroll
        for (int j = 0; j < 8; ++j) {
            int c = colbase + j;
            b[j] = (rowok && (unsigned)c < (unsigned)IMG) ? row[c] : 0.f;
        }
    }
}

__global__ void __launch_bounds__(256, 4)
ssim_mfma_kernel(const float* __restrict__ img1,
                 const float* __restrict__ img2,
                 float* __restrict__ acc)
{
    __shared__ __align__(16) _Float16 ht[5][64][RS];   // 35840 B
    __shared__ _Float16 wtab[12];
    __shared__ float wsum[4];

    const int tid   = threadIdx.x;
    const int lane  = tid & 63;
    const int w     = tid >> 6;          // wave id == horizontal nt / vertical nt
    const int row16 = lane & 15;
    const int g     = lane >> 4;
    const int c_n   = w * 16 + row16;    // this lane's H/OUT column (0..63)

    if (tid < 12) wtab[tid] = (tid < 11) ? (_Float16)GW[tid] : (_Float16)0.f;
    __syncthreads();

    // ---- horizontal B-frags: WH[u][c] = w[u - c - 3], u = kt*32 + g*8 + j ----
    f16x8 Bh[3];
#pragma unroll
    for (int kt = 0; kt < 3; ++kt)
#pragma unroll
        for (int j = 0; j < 8; ++j) {
            const int u = kt * 32 + g * 8 + j;
            Bh[kt][j] = wl(wtab, u - c_n - 3);
        }

    const size_t pbase = (size_t)blockIdx.z * IMG * IMG;
    const float* __restrict__ p1 = img1 + pbase;
    const float* __restrict__ p2 = img2 + pbase;
    const int gx0 = blockIdx.x * 64 - 8;
    const int gy0 = blockIdx.y * 32 - 5;

    // ================= Phase A: horizontal banded GEMM =================
#pragma unroll
    for (int mt = 0; mt < 3; ++mt) {
        f32x4 acch[5] = {{0,0,0,0},{0,0,0,0},{0,0,0,0},{0,0,0,0},{0,0,0,0}};
        const int  r_row = mt * 16 + row16;        // X/H row (0..47)
        const int  gy    = gy0 + r_row;
        const bool rowok = ((unsigned)gy < (unsigned)IMG);
        const int  gyc   = gy < 0 ? 0 : (gy > IMG - 1 ? IMG - 1 : gy);
        const float* __restrict__ r1 = p1 + (size_t)gyc * IMG;
        const float* __restrict__ r2 = p2 + (size_t)gyc * IMG;

#pragma unroll
        for (int kt = 0; kt < 3; ++kt) {
            const int colbase = gx0 + kt * 32 + g * 8;
            float b1[8], b2[8];
            loadrow8(r1, colbase, rowok, b1);
            loadrow8(r2, colbase, rowok, b2);
            f16x8 x1, x2;
#pragma unroll
            for (int j = 0; j < 8; ++j) { x1[j] = (_Float16)b1[j]; x2[j] = (_Float16)b2[j]; }
            const f16x8 p11 = x1 * x1;
            const f16x8 p22 = x2 * x2;
            const f16x8 p12 = x1 * x2;
            acch[0] = __builtin_amdgcn_mfma_f32_16x16x32_f16(x1,  Bh[kt], acch[0], 0, 0, 0);
            acch[1] = __builtin_amdgcn_mfma_f32_16x16x32_f16(x2,  Bh[kt], acch[1], 0, 0, 0);
            acch[2] = __builtin_amdgcn_mfma_f32_16x16x32_f16(p11, Bh[kt], acch[2], 0, 0, 0);
            acch[3] = __builtin_amdgcn_mfma_f32_16x16x32_f16(p22, Bh[kt], acch[3], 0, 0, 0);
            acch[4] = __builtin_amdgcn_mfma_f32_16x16x32_f16(p12, Bh[kt], acch[4], 0, 0, 0);
        }

        // C-frag -> ht (transposed store): rows mt*16+g*4+reg, col c_n
        const int r0 = mt * 16 + g * 4;
#pragma unroll
        for (int s = 0; s < 5; ++s) {
            f16x4 pv;
            pv[0] = (_Float16)acch[s][0];
            pv[1] = (_Float16)acch[s][1];
            pv[2] = (_Float16)acch[s][2];
            pv[3] = (_Float16)acch[s][3];
            *reinterpret_cast<f16x4*>(&ht[s][c_n][r0]) = pv;   // 8B store
        }
    }
    // No barrier: each wave reads back only the columns it wrote.

    // ================= Phase B: vertical banded GEMM + SSIM =================
    const float C1 = 1e-4f;
    const float C2 = 9e-4f;
    float local = 0.f;
#pragma unroll
    for (int mt = 0; mt < 2; ++mt) {
        f32x4 av[5] = {{0,0,0,0},{0,0,0,0},{0,0,0,0},{0,0,0,0},{0,0,0,0}};
        const int m = mt * 16 + row16;             // OUT row this lane supplies (A-frag)
#pragma unroll
        for (int kt = 0; kt < 2; ++kt) {
            const int kb = kt * 16;                // u window base: 0 or 16
            f16x8 aw;
#pragma unroll
            for (int j = 0; j < 8; ++j) {
                const int u = kb + g * 8 + j;
                _Float16 wv = wl(wtab, u - m);     // WV[m][u] = w[u-m]
                if (kt == 1 && u < 32) wv = (_Float16)0.f;   // avoid double-count of overlap
                aw[j] = wv;
            }
#pragma unroll
            for (int s = 0; s < 5; ++s) {
                const f16x8 b = *reinterpret_cast<const f16x8*>(&ht[s][c_n][kb + g * 8]);
                av[s] = __builtin_amdgcn_mfma_f32_16x16x32_f16(aw, b, av[s], 0, 0, 0);
            }
        }
#pragma unroll
        for (int reg = 0; reg < 4; ++reg) {
            const float mu1 = av[0][reg], mu2 = av[1][reg];
            const float e11 = av[2][reg], e22 = av[3][reg], e12 = av[4][reg];
            const float mu1sq = mu1 * mu1;
            const float mu2sq = mu2 * mu2;
            const float mu12  = mu1 * mu2;
            const float num = (2.f * mu12 + C1) * (2.f * (e12 - mu12) + C2);
            const float den = (mu1sq + mu2sq + C1) * ((e11 - mu1sq) + (e22 - mu2sq) + C2);
            local += num * __builtin_amdgcn_rcpf(den);
        }
    }

    // ---------- block reduction ----------
#pragma unroll
    for (int off = 32; off > 0; off >>= 1)
        local += __shfl_down(local, off, 64);
    if ((tid & 63) == 0) wsum[tid >> 6] = local;
    __syncthreads();
    if (tid == 0) {
        float t = wsum[0] + wsum[1] + wsum[2] + wsum[3];
        atomicAdd(acc, t);
    }
}

__global__ void zero_acc_kernel(float* acc) {
    if (threadIdx.x == 0) acc[0] = 0.f;
}

__global__ void finalize_kernel(const float* __restrict__ acc,
                                float* __restrict__ out) {
    if (threadIdx.x == 0)
        out[0] = 1.0f - acc[0] * (1.0f / (float)NPIX);
}

extern "C" void kernel_launch(void* const* d_in, const int* in_sizes, int n_in,
                              void* d_out, int out_size, void* d_ws, size_t ws_size,
                              hipStream_t stream) {
    const float* img1 = (const float*)d_in[0];
    const float* img2 = (const float*)d_in[1];
    float* out = (float*)d_out;
    float* acc = (float*)d_ws;

    zero_acc_kernel<<<1, 64, 0, stream>>>(acc);
    dim3 grid(IMG / 64, IMG / 32, NPLANES);   // (8, 16, 48) = 6144 blocks
    ssim_mfma_kernel<<<grid, 256, 0, stream>>>(img1, img2, acc);
    finalize_kernel<<<1, 64, 0, stream>>>(acc, out);
}